// Round 1
// baseline (561.584 us; speedup 1.0000x reference)
//
#include <hip/hip_runtime.h>
#include <hip/hip_bf16.h>

typedef __bf16 bf16_t;
typedef __bf16 bf16x8 __attribute__((ext_vector_type(8)));
typedef float f32x4 __attribute__((ext_vector_type(4)));

#define LOG2E 1.44269504088896340736f
#define LN2 0.69314718055994530942f

__device__ __forceinline__ float fast_exp2(float x) { return __builtin_amdgcn_exp2f(x); }
__device__ __forceinline__ float fast_log2(float x) { return __builtin_amdgcn_logf(x); }
__device__ __forceinline__ float fast_rcp(float x) { return __builtin_amdgcn_rcpf(x); }

__device__ __forceinline__ float softplus_f(float x) {
    float sp = LN2 * fast_log2(1.0f + fast_exp2(x * LOG2E));
    return (x > 20.0f) ? x : sp;
}
// tanh(x) = 1 - 2/(1+e^{2x}); inf-safe at both ends (exp2->inf => 1, exp2->0 => -1)
__device__ __forceinline__ float tanh_f(float x) {
    float e = fast_exp2(x * (2.0f * LOG2E));
    return 1.0f - 2.0f * fast_rcp(1.0f + e);
}

template <int CTRL>
__device__ __forceinline__ float dpp_add(float v) {
    int iv = __builtin_bit_cast(int, v);
    int sv = __builtin_amdgcn_update_dpp(0, iv, CTRL, 0xF, 0xF, true);
    return v + __builtin_bit_cast(float, sv);
}

// B=4096, L=64, C=7, H=32, K=2 -> 126 RK4 steps, h=0.5
// Block: 512 threads (8 waves), owns 16 batch rows. Grid: 256 blocks.
__global__ __launch_bounds__(512) void cde_kernel(
    const float* __restrict__ x,    // (4096,64,7)
    const float* __restrict__ Wi,   // (32,7)
    const float* __restrict__ bi,   // (32,)
    const float* __restrict__ W1,   // (32,32)
    const float* __restrict__ b1,   // (32,)
    const float* __restrict__ W2,   // (224,32)
    const float* __restrict__ b2,   // (224,)
    const float* __restrict__ Wo1,  // (16,32)
    const float* __restrict__ bo1,  // (16,)
    const float* __restrict__ Wo2,  // (3,16)
    const float* __restrict__ bo2,  // (3,)
    float* __restrict__ out)        // (4096,3)
{
    __shared__ float diffs[16][63 * 7];  // [r][i*7+c] = x[r][i+1][c]-x[r][i][c]
    __shared__ float zbase[16][32];
    __shared__ float kacc[16][32];
    __shared__ float kbuf[16][32];
    __shared__ float dxs[16][8];         // dXdt at current stage time; [.][7] == 0
    __shared__ bf16_t zhi[16][32], zlo[16][32];
    __shared__ bf16_t h1hi[16][32], h1lo[16][32];
    __shared__ float ubuf[16][16];

    const int tid = threadIdx.x;
    const int l = tid & 63;
    const int w = tid >> 6;      // wave 0..7
    const int r0 = blockIdx.x * 16;

    // MFMA 16x16x32 lane mapping:
    //  A: row = l&15, k = (l>>4)*8 + j   (bf16x8)
    //  B: col = l&15, k = (l>>4)*8 + j   (bf16x8)
    //  C/D: col = l&15, row = (l>>4)*4 + reg  (f32x4)   [m89-verified]
    const int ar = l & 15;
    const int ak = (l >> 4) * 8;
    const int crow = (l >> 4) * 4;
    const int T1 = w >> 2;   // GEMV1 tile this wave computes (0/1)
    const int rw = w & 3;    // C-reg this wave softplus-es

    // ---- preload weight fragments (hi/lo bf16 split for ~f32 precision) ----
    bf16x8 w1h, w1l;
    {
        const float* p = &W1[(16 * T1 + ar) * 32 + ak];
#pragma unroll
        for (int j = 0; j < 8; ++j) {
            float v = p[j];
            bf16_t hh = (bf16_t)v;
            w1h[j] = hh;
            w1l[j] = (bf16_t)(v - (float)hh);
        }
    }
    const float b1c = b1[16 * T1 + ar];

    bf16x8 w2h[2], w2l[2];
    float b2c[2];
#pragma unroll
    for (int T2 = 0; T2 < 2; ++T2) {
        int N = 32 * w + 16 * T2 + ar;   // padded col 0..255
        int hcol = N >> 3, ccol = N & 7;
        if (ccol < 7) {
            const float* p = &W2[(hcol * 7 + ccol) * 32 + ak];
#pragma unroll
            for (int j = 0; j < 8; ++j) {
                float v = p[j];
                bf16_t hh = (bf16_t)v;
                w2h[T2][j] = hh;
                w2l[T2][j] = (bf16_t)(v - (float)hh);
            }
            b2c[T2] = b2[hcol * 7 + ccol];
        } else {
#pragma unroll
            for (int j = 0; j < 8; ++j) { w2h[T2][j] = (bf16_t)0.0f; w2l[T2][j] = (bf16_t)0.0f; }
            b2c[T2] = 0.0f;
        }
    }

    // ---- spline diffs into LDS ----
    for (int e = tid; e < 16 * 441; e += 512) {
        int r = e / 441, rem = e - r * 441;   // rem = i*7+c
        const float* px = &x[(size_t)(r0 + r) * 448];
        diffs[r][rem] = px[rem + 7] - px[rem];
    }
    // ---- z0 = x[:,0] @ Wi^T + bi ----
    {
        int r = tid >> 5, hh = tid & 31;
        const float* px = &x[(size_t)(r0 + r) * 448];
        float acc = bi[hh];
#pragma unroll
        for (int c = 0; c < 7; ++c) acc += px[c] * Wi[hh * 7 + c];
        zbase[r][hh] = acc;
        bf16_t zh = (bf16_t)acc;
        zhi[r][hh] = zh;
        zlo[r][hh] = (bf16_t)(acc - (float)zh);
    }
    if (tid < 16) dxs[tid][7] = 0.0f;
    __syncthreads();

    const int r_u = tid >> 5, h_u = tid & 31;
    const int rdx = tid / 7, cdx = tid - (tid / 7) * 7;  // valid for tid<112

    for (int it = 0; it < 504; ++it) {
        const int s = it & 3;
        const int k = it >> 2;

        // dXdt at this stage time (k2 and k3 share t+h/2 -> skip s==2)
        if (s != 2 && tid < 112) {
            int m = 2 * k + ((s == 0) ? 0 : (s == 3) ? 2 : 1);  // t = 0.25*m
            int i = m >> 2;
            if (i > 62) i = 62;
            float f = 0.25f * (float)(m - 4 * i);
            float D = diffs[rdx][i * 7 + cdx];
            float a = diffs[rdx][(i > 0 ? i - 1 : 0) * 7 + cdx];
            // cb + (two_c + three_d*f)*f == a + (D-a)*f*(4-3f)
            dxs[rdx][cdx] = a + (D - a) * (f * (4.0f - 3.0f * f));
        }

        // GEMV1: h1 = softplus(z @ W1^T + b1)   (each wave: tile T1, extract reg rw)
        {
            bf16x8 azh = *(const bf16x8*)&zhi[ar][ak];
            bf16x8 azl = *(const bf16x8*)&zlo[ar][ak];
            f32x4 d1 = {b1c, b1c, b1c, b1c};
            d1 = __builtin_amdgcn_mfma_f32_16x16x32_bf16(azh, w1h, d1, 0, 0, 0);
            d1 = __builtin_amdgcn_mfma_f32_16x16x32_bf16(azl, w1h, d1, 0, 0, 0);
            d1 = __builtin_amdgcn_mfma_f32_16x16x32_bf16(azh, w1l, d1, 0, 0, 0);
            float sp = softplus_f(d1[rw]);
            bf16_t sh = (bf16_t)sp;
            h1hi[crow + rw][16 * T1 + ar] = sh;
            h1lo[crow + rw][16 * T1 + ar] = (bf16_t)(sp - (float)sh);
        }
        __syncthreads();

        // GEMV2 + tanh + contract over c (c == lane&7, pad c=7 contributes 0)
        {
            bf16x8 ahh = *(const bf16x8*)&h1hi[ar][ak];
            bf16x8 ahl = *(const bf16x8*)&h1lo[ar][ak];
            float dxv[4];
#pragma unroll
            for (int r = 0; r < 4; ++r) dxv[r] = dxs[crow + r][l & 7];
#pragma unroll
            for (int T2 = 0; T2 < 2; ++T2) {
                f32x4 d2 = {b2c[T2], b2c[T2], b2c[T2], b2c[T2]};
                d2 = __builtin_amdgcn_mfma_f32_16x16x32_bf16(ahh, w2h[T2], d2, 0, 0, 0);
                d2 = __builtin_amdgcn_mfma_f32_16x16x32_bf16(ahl, w2h[T2], d2, 0, 0, 0);
                d2 = __builtin_amdgcn_mfma_f32_16x16x32_bf16(ahh, w2l[T2], d2, 0, 0, 0);
#pragma unroll
                for (int r = 0; r < 4; ++r) {
                    float g = tanh_f(d2[r]);
                    float v = g * dxv[r];
                    v = dpp_add<0xB1>(v);    // + lane^1 (quad_perm [1,0,3,2])
                    v = dpp_add<0x4E>(v);    // + lane^2 (quad_perm [2,3,0,1])
                    v = dpp_add<0x141>(v);   // + other quad (row_half_mirror)
                    if ((l & 7) == 0)
                        kbuf[crow + r][4 * w + 2 * T2 + ((l >> 3) & 1)] = v;
                }
            }
        }
        __syncthreads();

        // RK4 state update (1 value per thread)
        {
            float kv = kbuf[r_u][h_u];
            float zb = zbase[r_u][h_u];
            float zs;
            if (s == 0) {
                kacc[r_u][h_u] = kv;
                zs = zb + 0.25f * kv;           // z + 0.5*h*k1
            } else if (s == 1) {
                kacc[r_u][h_u] += 2.0f * kv;
                zs = zb + 0.25f * kv;           // z + 0.5*h*k2
            } else if (s == 2) {
                kacc[r_u][h_u] += 2.0f * kv;
                zs = zb + 0.5f * kv;            // z + h*k3
            } else {
                float zn = zb + (1.0f / 12.0f) * (kacc[r_u][h_u] + kv);  // h/6
                zbase[r_u][h_u] = zn;
                zs = zn;
            }
            bf16_t zh = (bf16_t)zs;
            zhi[r_u][h_u] = zh;
            zlo[r_u][h_u] = (bf16_t)(zs - (float)zh);
        }
        __syncthreads();
    }

    // ---- output head: out = softplus(z @ Wo1^T + bo1) @ Wo2^T + bo2 ----
    {   // Wo1 transposed into kbuf (now free)
        int hh = tid >> 4, jj = tid & 15;
        ((float*)kbuf)[hh * 16 + jj] = Wo1[jj * 32 + hh];
    }
    __syncthreads();
    if (tid < 256) {
        int r = tid >> 4, jj = tid & 15;
        const float* kf = (const float*)kbuf;
        float acc = bo1[jj];
#pragma unroll
        for (int hh = 0; hh < 32; ++hh) acc += zbase[r][hh] * kf[hh * 16 + jj];
        ubuf[r][jj] = softplus_f(acc);
    }
    __syncthreads();
    if (tid < 48) {
        int r = tid / 3, o = tid - (tid / 3) * 3;
        float acc = bo2[o];
#pragma unroll
        for (int j = 0; j < 16; ++j) acc += ubuf[r][j] * Wo2[o * 16 + j];
        out[(size_t)(r0 + r) * 3 + o] = acc;
    }
}

extern "C" void kernel_launch(void* const* d_in, const int* in_sizes, int n_in,
                              void* d_out, int out_size, void* d_ws, size_t ws_size,
                              hipStream_t stream) {
    (void)in_sizes; (void)n_in; (void)d_ws; (void)ws_size; (void)out_size;
    const float* x   = (const float*)d_in[0];
    const float* Wi  = (const float*)d_in[1];
    const float* bi  = (const float*)d_in[2];
    const float* W1  = (const float*)d_in[3];
    const float* b1  = (const float*)d_in[4];
    const float* W2  = (const float*)d_in[5];
    const float* b2  = (const float*)d_in[6];
    const float* Wo1 = (const float*)d_in[7];
    const float* bo1 = (const float*)d_in[8];
    const float* Wo2 = (const float*)d_in[9];
    const float* bo2 = (const float*)d_in[10];
    cde_kernel<<<dim3(256), dim3(512), 0, stream>>>(x, Wi, bi, W1, b1, W2, b2,
                                                    Wo1, bo1, Wo2, bo2, (float*)d_out);
}